// Round 3
// baseline (227.156 us; speedup 1.0000x reference)
//
#include <hip/hip_runtime.h>
#include <stdint.h>

#define BB    2048
#define DIN   4096
#define DOUT  4096
#define NW    64      // 64-bit words per DIN bits

// ---------------------------------------------------------------------------
// ws layout:
//   xp  : [NW][BB]   u64   offset 0        (1 MB)   bits of x rows
//   mp  : [NW][DOUT] u64   offset 1 MB     (2 MB)   bits of mask columns
//
// Output is int32 0/1 (harness materializes the bool reference as int32).
// Mask dtype (u8-bool vs int32) is detected inline in pack_m via a wave
// reduction over the first 1 KB: E[sum] = 128 (u8) vs 32 (int32), 8 sigma.
// ---------------------------------------------------------------------------

// Pack x (2048 x 4096 int32 of {0,1}) into xp[w][b]. One block per row;
// each wave ballots 64 coalesced elements into one u64 word.
__global__ void pack_x(const int* __restrict__ x,
                       unsigned long long* __restrict__ xp) {
    const int b    = blockIdx.x;
    const int tid  = threadIdx.x;
    const int wv   = tid >> 6;     // wave in block, 0..3
    const int lane = tid & 63;
    const int* row = x + (size_t)b * DIN;
    #pragma unroll
    for (int j = 0; j < 16; ++j) {
        int v = row[j * 256 + tid];
        unsigned long long word = __ballot(v != 0);
        if (lane == 0) xp[(size_t)(j * 4 + wv) * BB + b] = word;
    }
}

// Pack mask columns into mp[w][o]. Block = (w, o-tile of 1024); each thread
// builds 4 adjacent columns' words from 64 coalesced row reads (fully
// unrolled -> 64 loads in flight -> HBM-throughput-bound, not latency).
__global__ void pack_m(const void* __restrict__ mraw,
                       unsigned long long* __restrict__ mp) {
    const int w   = blockIdx.x;              // 0..63
    const int o0  = blockIdx.y * 1024;
    const int tid = threadIdx.x;
    const int o   = o0 + tid * 4;

    // inline dtype detect: 4 bytes/thread from the first 1 KB, wave-reduce.
    const unsigned char* mb = (const unsigned char*)mraw;
    int myv = (mb[tid] != 0) + (mb[tid + 256] != 0) +
              (mb[tid + 512] != 0) + (mb[tid + 768] != 0);
    #pragma unroll
    for (int d = 32; d; d >>= 1) myv += __shfl_xor(myv, d);
    const bool isU8 = (myv > 64);   // u8-bool ~128, int32 ~32 per wave

    unsigned long long w0 = 0, w1 = 0, w2 = 0, w3 = 0;
    if (isU8) {
        const unsigned int* m8 = (const unsigned int*)mraw;  // 4 bool bytes
        #pragma unroll
        for (int k = 0; k < 64; ++k) {
            unsigned int v = m8[(size_t)(w * 64 + k) * (DOUT / 4) + (o >> 2)];
            unsigned long long bit = 1ull << k;
            if (v & 0x000000ffu) w0 |= bit;
            if (v & 0x0000ff00u) w1 |= bit;
            if (v & 0x00ff0000u) w2 |= bit;
            if (v & 0xff000000u) w3 |= bit;
        }
    } else {
        const int4* m32 = (const int4*)mraw;
        #pragma unroll
        for (int k = 0; k < 64; ++k) {
            int4 v = m32[(size_t)(w * 64 + k) * (DOUT / 4) + (o >> 2)];
            unsigned long long bit = 1ull << k;
            if (v.x) w0 |= bit;
            if (v.y) w1 |= bit;
            if (v.z) w2 |= bit;
            if (v.w) w3 |= bit;
        }
    }
    unsigned long long* dst = mp + (size_t)w * DOUT + o;
    dst[0] = w0; dst[1] = w1; dst[2] = w2; dst[3] = w3;
}

// Bit-GEMM: 128x128 tile per block, 256 threads, 8x8 register tile each.
// Ownership interleaved at stride 32 so LDS reads are contiguous 16B per
// lane-group (<=2-way bank aliasing, free). K staged in 16-word chunks with
// register prefetch of the next chunk issued under the compute phase.
__global__ __launch_bounds__(256, 2)
void bgemm(const unsigned long long* __restrict__ xp,
           const unsigned long long* __restrict__ mp,
           const int* __restrict__ thr,
           int* __restrict__ out) {
    const int o0  = blockIdx.x * 128;
    const int b0  = blockIdx.y * 128;
    const int tid = threadIdx.x;
    const int tx  = tid & 15;   // o dimension
    const int ty  = tid >> 4;   // b dimension

    __shared__ unsigned long long ldsx[16 * 128];
    __shared__ unsigned long long ldsm[16 * 128];

    unsigned int acc[8][8];
    #pragma unroll
    for (int i = 0; i < 8; ++i)
        #pragma unroll
        for (int j = 0; j < 8; ++j) acc[i][j] = 0;

    ulonglong2 px[4], pm4[4];
    auto load_chunk = [&](int chunk) {
        const int wbase = chunk * 16;
        #pragma unroll
        for (int q = 0; q < 4; ++q) {
            int p  = q * 256 + tid;      // u64-pair index, 0..1023
            int w  = p >> 6;             // 0..15
            int b2 = (p & 63) * 2;       // 0..126 even
            px[q]  = *(const ulonglong2*)(xp + (size_t)(wbase + w) * BB + b0 + b2);
            pm4[q] = *(const ulonglong2*)(mp + (size_t)(wbase + w) * DOUT + o0 + b2);
        }
    };

    load_chunk(0);
    for (int chunk = 0; chunk < 4; ++chunk) {
        // regs -> LDS
        #pragma unroll
        for (int q = 0; q < 4; ++q) {
            int p  = q * 256 + tid;
            int w  = p >> 6;
            int b2 = (p & 63) * 2;
            *(ulonglong2*)(ldsx + w * 128 + b2) = px[q];
            *(ulonglong2*)(ldsm + w * 128 + b2) = pm4[q];
        }
        __syncthreads();

        // prefetch next chunk while computing this one
        if (chunk < 3) load_chunk(chunk + 1);

        #pragma unroll 2
        for (int w = 0; w < 16; ++w) {
            unsigned long long xv[8], mv[8];
            #pragma unroll
            for (int r = 0; r < 4; ++r) {
                ulonglong2 t = *(const ulonglong2*)(ldsx + w * 128 + ty * 2 + r * 32);
                xv[2 * r]     = t.x;
                xv[2 * r + 1] = t.y;
                ulonglong2 u = *(const ulonglong2*)(ldsm + w * 128 + tx * 2 + r * 32);
                mv[2 * r]     = u.x;
                mv[2 * r + 1] = u.y;
            }
            #pragma unroll
            for (int i = 0; i < 8; ++i)
                #pragma unroll
                for (int j = 0; j < 8; ++j)
                    acc[i][j] += __builtin_popcountll(xv[i] ^ mv[j]);
        }
        __syncthreads();
    }

    // epilogue: sums = 4096 - X; out = (sums > thr) = (X < 4096 - thr)
    // write int32 0/1 (reference bool -> int32 in the harness)
    int limj[8];
    #pragma unroll
    for (int j = 0; j < 8; ++j)
        limj[j] = DIN - thr[o0 + tx * 2 + (j >> 1) * 32 + (j & 1)];

    #pragma unroll
    for (int i = 0; i < 8; ++i) {
        int b = b0 + ty * 2 + (i >> 1) * 32 + (i & 1);
        int* orow = out + (size_t)b * DOUT + o0;
        #pragma unroll
        for (int j2 = 0; j2 < 4; ++j2) {
            int2 v;
            v.x = ((int)acc[i][2 * j2]     < limj[2 * j2])     ? 1 : 0;
            v.y = ((int)acc[i][2 * j2 + 1] < limj[2 * j2 + 1]) ? 1 : 0;
            *(int2*)(orow + tx * 2 + j2 * 32) = v;
        }
    }
}

extern "C" void kernel_launch(void* const* d_in, const int* in_sizes, int n_in,
                              void* d_out, int out_size, void* d_ws, size_t ws_size,
                              hipStream_t stream) {
    const int* x          = (const int*)d_in[0];
    const void* masks     = d_in[1];           // bool: u8 or int32 (detected inline)
    const int* thresholds = (const int*)d_in[2];
    int* out              = (int*)d_out;

    unsigned long long* xp = (unsigned long long*)d_ws;                          // 1 MB
    unsigned long long* mp = (unsigned long long*)((char*)d_ws + (1 << 20));     // 2 MB

    pack_x<<<BB, 256, 0, stream>>>(x, xp);
    pack_m<<<dim3(NW, 4), 256, 0, stream>>>(masks, mp);
    bgemm<<<dim3(DOUT / 128, BB / 128), 256, 0, stream>>>(xp, mp, thresholds, out);
}